// Round 15
// baseline (677.596 us; speedup 1.0000x reference)
//
#include <hip/hip_runtime.h>
#include <cstdint>
#include <cstddef>

// ---------------------------------------------------------------------------
// MultiStageDiT round 15: GEMM re-geometried for occupancy: 128x128 tile,
// 8 waves (4Mx2N), per-wave 32x64 output (acc = 32 AGPRs), 64KB LDS dbuf,
// launch_bounds(512,4) -> ~110 regs -> 4 waves/SIMD -> 2 blocks/CU
// (previous: 240 regs + 128KB LDS = 1 block/CU, MfmaUtil capped at 35%).
// Same round-11 flow: 1 barrier + 1 vmcnt(0) per K-tile.
// attn (merged tables, spill-free) / LN / prep unchanged from round 14 (630us).
// ---------------------------------------------------------------------------

typedef float  f32x4    __attribute__((ext_vector_type(4)));
typedef __bf16 bf16x8_t __attribute__((ext_vector_type(8)));
typedef __bf16 bf16x4_t __attribute__((ext_vector_type(4)));

#define DEV __device__ __forceinline__

DEV void gload_lds16(const void* g, void* l) {
    auto gp = (const uint32_t __attribute__((address_space(1)))*)(uintptr_t)g;
    auto lp = (uint32_t __attribute__((address_space(3)))*)(uint32_t)(uintptr_t)l;
    __builtin_amdgcn_global_load_lds(gp, lp, 16, 0, 0);
}

// row-major LDS tile, 16B chunks XOR-swizzled by (row&7)
DEV bf16x8_t lds_frag(const __bf16* base, int row, int chunk, int row_elems) {
    return *(const bf16x8_t*)(base + row * row_elems + ((chunk ^ (row & 7)) << 3));
}

// 32-elem-row P tile: XOR key (row>>1)&3
DEV bf16x8_t p_frag(const __bf16* base, int row, int chunk) {
    return *(const bf16x8_t*)(base + row * 32 + ((chunk ^ ((row >> 1) & 3)) << 3));
}

// V^T tile elem address: key (d&7)^((d>>3)&7)
DEV int vt_addr(int d, int k) {
    return d * 64 + ((((k >> 3) ^ (d & 7) ^ ((d >> 3) & 7)) << 3) | (k & 7));
}

DEV float gelu_tanh(float v) {
    float u = 0.7978845608028654f * (v + 0.044715f * v * v * v);
    float e = __expf(2.f * u);
    float th = 1.f - 2.f / (e + 1.f);
    return 0.5f * v * (1.f + th);
}

DEV int win2tok(int r) {
    int nb = r >> 12, wi = (r >> 8) & 15, l = r & 255;
    return (nb << 12) + (wi >> 2) * 1024 + (l >> 4) * 64 + (wi & 3) * 16 + (l & 15);
}

// ---------------------------------------------------------------------------
// prep kernels
// ---------------------------------------------------------------------------
__global__ void silu_k(const float* __restrict__ c, float* __restrict__ o, int n) {
    int i = blockIdx.x * 256 + threadIdx.x;
    if (i < n) { float v = c[i]; o[i] = v / (1.f + __expf(-v)); }
}

__global__ void zero_k(float* o, int n) {
    int i = blockIdx.x * 256 + threadIdx.x;
    if (i < n) o[i] = 0.f;
}

__global__ void conv_bf16(const float* __restrict__ s, __bf16* __restrict__ d, int n4) {
    int i = blockIdx.x * 256 + threadIdx.x;
    if (i < n4) {
        float4 v = ((const float4*)s)[i];
        bf16x4_t o; o[0] = (__bf16)v.x; o[1] = (__bf16)v.y; o[2] = (__bf16)v.z; o[3] = (__bf16)v.w;
        ((bf16x4_t*)d)[i] = o;
    }
}

__global__ __launch_bounds__(256)
void mod_gemv(const float* __restrict__ sc, const float* __restrict__ w,
              const float* __restrict__ b, float* __restrict__ mod) {
    int o = (blockIdx.x << 2) + (threadIdx.x >> 6);
    int lane = threadIdx.x & 63;
    int n = o / 6144, col = o % 6144;
    const float4* wr = (const float4*)(w + (size_t)col * 1024);
    const float4* sr = (const float4*)(sc + n * 1024);
    float acc = 0.f;
    #pragma unroll 4
    for (int i = lane; i < 256; i += 64) {
        float4 a = wr[i], x = sr[i];
        acc += a.x * x.x + a.y * x.y + a.z * x.z + a.w * x.w;
    }
    #pragma unroll
    for (int m = 1; m < 64; m <<= 1) acc += __shfl_xor(acc, m);
    if (lane == 0) mod[o] = acc + b[col];
}

__global__ __launch_bounds__(256)
void ln_mod_k(const float* __restrict__ src, const float* __restrict__ mod,
              int sh_off, int sc_off, __bf16* __restrict__ out, int permute, int r0) {
    int rl = blockIdx.x;
    int r = rl + r0;
    int nb = r >> 12;
    int t = permute ? win2tok(r) : r;
    float4 v = ((const float4*)(src + (size_t)t * 1024))[threadIdx.x];
    float s  = v.x + v.y + v.z + v.w;
    float sq = v.x * v.x + v.y * v.y + v.z * v.z + v.w * v.w;
    #pragma unroll
    for (int m = 1; m < 64; m <<= 1) { s += __shfl_xor(s, m); sq += __shfl_xor(sq, m); }
    __shared__ float ps[4], pq[4];
    int wv = threadIdx.x >> 6, ln = threadIdx.x & 63;
    if (ln == 0) { ps[wv] = s; pq[wv] = sq; }
    __syncthreads();
    s  = ps[0] + ps[1] + ps[2] + ps[3];
    sq = pq[0] + pq[1] + pq[2] + pq[3];
    float mean = s * (1.f / 1024.f);
    float var  = sq * (1.f / 1024.f) - mean * mean;
    float rstd = rsqrtf(var + 1e-6f);
    int c = threadIdx.x << 2;
    const float* mrow = mod + nb * 6144;
    float4 scv = *(const float4*)(mrow + sc_off + c);
    float4 shv = *(const float4*)(mrow + sh_off + c);
    bf16x4_t o;
    o[0] = (__bf16)((v.x - mean) * rstd * (1.f + scv.x) + shv.x);
    o[1] = (__bf16)((v.y - mean) * rstd * (1.f + scv.y) + shv.y);
    o[2] = (__bf16)((v.z - mean) * rstd * (1.f + scv.z) + shv.z);
    o[3] = (__bf16)((v.w - mean) * rstd * (1.f + scv.w) + shv.w);
    *(bf16x4_t*)(out + (size_t)rl * 1024 + c) = o;
}

// ---------------------------------------------------------------------------
// 128x128 bf16 GEMM, 8 waves (4Mx2N), per-wave 32x64, 64KB LDS dbuf,
// launch_bounds(512,4) for 2 blocks/CU. Round-11 flow: per K-tile
// {vmcnt(0); barrier; stage t+1 -> buf^1; read frags; 16 MFMA}.
// EPI: 0 bf16 | 1 win2tok scatter residual f32 | 2 gelu->bf16 | 3 residual f32
// ---------------------------------------------------------------------------
#define GBAR  __builtin_amdgcn_s_barrier()
#define PRIO1 __builtin_amdgcn_s_setprio(1)
#define PRIO0 __builtin_amdgcn_s_setprio(0)

template <int EPI>
__global__ __launch_bounds__(512, 4)
void gemmw8(const __bf16* __restrict__ A, const __bf16* __restrict__ B,
            const float* __restrict__ bias, void* __restrict__ Cout,
            const float* __restrict__ extra, const float* __restrict__ mod,
            int N, int K, int r0, int gx) {
    extern __shared__ __align__(16) char smem[];
    __bf16* lA = (__bf16*)smem;             // [2][128*64]  (32 KB)
    __bf16* lB = lA + 2 * 8192;             // [2][128*64]  (32 KB)
    const int tid = threadIdx.x, lane = tid & 63, wv = tid >> 6;
    const int wr = wv >> 1, wc = wv & 1;

    // bijective XCD-aware block swizzle (1-D grid)
    const int nwg = gridDim.x;
    const int qq = nwg >> 3, rr8 = nwg & 7;
    const int xcd = blockIdx.x & 7, pos = blockIdx.x >> 3;
    const int nid = (xcd < rr8 ? xcd * (qq + 1) : rr8 * (qq + 1) + (xcd - rr8) * qq) + pos;
    const int bm = (nid / gx) << 7, bn = (nid % gx) << 7;

    f32x4 acc[2][4];
    const f32x4 z4 = {0.f, 0.f, 0.f, 0.f};
    #pragma unroll
    for (int i = 0; i < 2; ++i)
        #pragma unroll
        for (int j = 0; j < 4; ++j) acc[i][j] = z4;

    bf16x8_t fa[2][2], fb[4][2];

    // ---- persistent stage pointers: wave w stages rows [w*16, w*16+16) ----
    const int l8  = lane >> 3;
    const int gc8 = ((lane & 7) ^ l8) << 3;          // pre-swizzled src chunk
    const int rw  = (wv << 4) + l8;
    const __bf16* gA0 = A + (size_t)(bm + rw)     * K + gc8;
    const __bf16* gA1 = A + (size_t)(bm + rw + 8) * K + gc8;
    const __bf16* gB0 = B + (size_t)(bn + rw)     * K + gc8;
    const __bf16* gB1 = B + (size_t)(bn + rw + 8) * K + gc8;
    const int d0 = (wv << 4) * 64, d1 = ((wv << 4) + 8) * 64;

    auto stageAll = [&](int be2) {
        gload_lds16(gA0, lA + be2 + d0); gload_lds16(gA1, lA + be2 + d1);
        gload_lds16(gB0, lB + be2 + d0); gload_lds16(gB1, lB + be2 + d1);
        gA0 += 64; gA1 += 64; gB0 += 64; gB1 += 64;
    };

    // ---- precomputed ds_read fragment bases ----
    // A row = wr*32 + mi*16 + (lane&15); B row = wc*64 + ni*16 + (lane&15);
    // chunk = ks*4 + (lane>>4), XOR (row&7)=(lane&7) -> swzb (+4 for ks=1).
    const int swzb = (lane >> 4) ^ (lane & 7);
    const __bf16* aR0 = lA + (wr << 11) + ((lane & 15) << 6) + (swzb << 3);
    const __bf16* aR1 = lA + (wr << 11) + ((lane & 15) << 6) + ((swzb ^ 4) << 3);
    const __bf16* bR0 = lB + (wc << 12) + ((lane & 15) << 6) + (swzb << 3);
    const __bf16* bR1 = lB + (wc << 12) + ((lane & 15) << 6) + ((swzb ^ 4) << 3);

    const int nt = K >> 6;
    stageAll(0);                          // prologue: tile 0 -> buf 0

    int be = 0;
    for (int t = 0; t < nt; ++t) {
        asm volatile("s_waitcnt vmcnt(0)" ::: "memory");  // prev stage landed
        GBAR;                              // all waves done reading old buf
        if (t + 1 < nt) stageAll(be ^ 8192);
        #pragma unroll
        for (int mi = 0; mi < 2; ++mi) {
            fa[mi][0] = *(const bf16x8_t*)(aR0 + be + mi * 1024);
            fa[mi][1] = *(const bf16x8_t*)(aR1 + be + mi * 1024);
        }
        #pragma unroll
        for (int ni = 0; ni < 4; ++ni) {
            fb[ni][0] = *(const bf16x8_t*)(bR0 + be + ni * 1024);
            fb[ni][1] = *(const bf16x8_t*)(bR1 + be + ni * 1024);
        }
        PRIO1;
        #pragma unroll
        for (int ks = 0; ks < 2; ++ks)
            #pragma unroll
            for (int mi = 0; mi < 2; ++mi)
                #pragma unroll
                for (int ni = 0; ni < 4; ++ni)
                    acc[mi][ni] = __builtin_amdgcn_mfma_f32_16x16x32_bf16(
                        fa[mi][ks], fb[ni][ks], acc[mi][ni], 0, 0, 0);
        PRIO0;
        be ^= 8192;
    }

    // ---- epilogue ----
    #pragma unroll
    for (int mi = 0; mi < 2; ++mi) {
        #pragma unroll
        for (int j = 0; j < 4; ++j) {
            int m = bm + (wr << 5) + (mi << 4) + ((lane >> 4) << 2) + j;
            #pragma unroll
            for (int ni = 0; ni < 4; ++ni) {
                int n = bn + (wc << 6) + (ni << 4) + (lane & 15);
                float v = acc[mi][ni][j] + bias[n];
                if constexpr (EPI == 0) {
                    ((__bf16*)Cout)[(size_t)m * N + n] = (__bf16)v;
                } else if constexpr (EPI == 1) {
                    int mg = m + r0;
                    int tr = win2tok(mg);
                    float g = mod[(mg >> 12) * 6144 + 2048 + n];
                    ((float*)Cout)[(size_t)tr * 1024 + n] = extra[(size_t)tr * 1024 + n] + g * v;
                } else if constexpr (EPI == 2) {
                    ((__bf16*)Cout)[(size_t)m * N + n] = (__bf16)gelu_tanh(v);
                } else {
                    int mg = m + r0;
                    float g = mod[(mg >> 12) * 6144 + 5120 + n];
                    ((float*)Cout)[(size_t)mg * 1024 + n] = extra[(size_t)mg * 1024 + n] + g * v;
                }
            }
        }
    }
}

// ---------------------------------------------------------------------------
// Window attention + inline rel-pos tables (round-14, spill-free, passing).
// ---------------------------------------------------------------------------
__global__ __launch_bounds__(256, 3)
void attn_k(const __bf16* __restrict__ qkv, const float* __restrict__ relh,
            const float* __restrict__ relw, __bf16* __restrict__ out) {
    __shared__ __align__(16) __bf16 lP[4][32 * 32];
    __shared__ __align__(16) __bf16 lKt[2][64 * 64];
    __shared__ __align__(16) __bf16 lVt[2][64 * 64];
    __shared__ __align__(16) __bf16 lTab[128 * 32];

    const int blk = blockIdx.x;
    const int winc = blk >> 5, h = (blk >> 1) & 15, qh = blk & 1;
    const int tid = threadIdx.x, lane = tid & 63, wv = tid >> 6;
    const __bf16* base = qkv + (size_t)winc * 256 * 3072 + h * 64;
    const int q0 = qh << 7;

    {
        __bf16* lR0 = lKt[0];
        __bf16* lR1 = lKt[1];
        for (int i = tid; i < 1984; i += 256) {
            int row = i >> 6, c = i & 63;
            lR0[row * 72 + c] = (__bf16)relh[i];
            lR1[row * 72 + c] = (__bf16)relw[i];
        }
    }
    __syncthreads();
    {
        const int r = tid >> 1, half = tid & 1;
        const int lwin = q0 + r;
        const int qi = lwin >> 4, qj = lwin & 15;
        const __bf16* qrow = base + (size_t)lwin * 3072;
        float ah[8], aw[8];
        #pragma unroll
        for (int kk = 0; kk < 8; ++kk) { ah[kk] = 0.f; aw[kk] = 0.f; }
        for (int c8 = 0; c8 < 8; ++c8) {
            bf16x8_t q8 = *(const bf16x8_t*)(qrow + (c8 << 3));
            float qf8[8];
            #pragma unroll
            for (int e = 0; e < 8; ++e) qf8[e] = (float)q8[e];
            #pragma unroll
            for (int kk = 0; kk < 8; ++kk) {
                int kg = (half << 3) + kk;
                bf16x8_t r1 = *(const bf16x8_t*)(lKt[0] + (qi - kg + 15) * 72 + (c8 << 3));
                bf16x8_t r2 = *(const bf16x8_t*)(lKt[1] + (qj - kg + 15) * 72 + (c8 << 3));
                float a1 = 0.f, a2 = 0.f;
                #pragma unroll
                for (int e = 0; e < 8; ++e) {
                    a1 += qf8[e] * (float)r1[e];
                    a2 += qf8[e] * (float)r2[e];
                }
                ah[kk] += a1; aw[kk] += a2;
            }
        }
        bf16x8_t oh, ow;
        #pragma unroll
        for (int kk = 0; kk < 8; ++kk) { oh[kk] = (__bf16)ah[kk]; ow[kk] = (__bf16)aw[kk]; }
        *(bf16x8_t*)(lTab + r * 32 + (half << 3))      = oh;
        *(bf16x8_t*)(lTab + r * 32 + 16 + (half << 3)) = ow;
    }
    __syncthreads();

    bf16x8_t qf[2][2];
    #pragma unroll
    for (int mi = 0; mi < 2; ++mi)
        #pragma unroll
        for (int ks = 0; ks < 2; ++ks) {
            int l = q0 + (wv << 5) + (mi << 4) + (lane & 15);
            qf[mi][ks] = *(const bf16x8_t*)(base + (size_t)l * 3072 + (((ks << 2) + (lane >> 4)) << 3));
        }
    {
        const __bf16* kb = base + 1024;
        #pragma unroll
        for (int q = 0; q < 2; ++q) {
            int c = (wv << 1) + q;
            int kl = (c << 3) + (lane >> 3);
            gload_lds16(kb + (size_t)kl * 3072 + (((lane & 7) ^ (lane >> 3)) << 3),
                        lKt[0] + c * 512);
        }
        const __bf16* vb = base + 2048;
        bf16x8_t a = *(const bf16x8_t*)(vb + (size_t)(tid >> 3) * 3072 + ((tid & 7) << 3));
        bf16x8_t b = *(const bf16x8_t*)(vb + (size_t)(32 + (tid >> 3)) * 3072 + ((tid & 7) << 3));
        int lc = tid & 7;
        #pragma unroll
        for (int e = 0; e < 8; ++e) {
            lVt[0][vt_addr(lc * 8 + e, tid >> 3)]        = a[e];
            lVt[0][vt_addr(lc * 8 + e, 32 + (tid >> 3))] = b[e];
        }
    }
    __syncthreads();

    float twv[2][4];
    #pragma unroll
    for (int mi = 0; mi < 2; ++mi)
        #pragma unroll
        for (int j = 0; j < 4; ++j) {
            int qr = (wv << 5) + (mi << 4) + ((lane >> 4) << 2) + j;
            twv[mi][j] = (float)lTab[qr * 32 + 16 + (lane & 15)];
        }

    const f32x4 z4 = {0.f, 0.f, 0.f, 0.f};
    f32x4 oacc[2][4];
    #pragma unroll
    for (int a = 0; a < 2; ++a)
        #pragma unroll
        for (int b = 0; b < 4; ++b) oacc[a][b] = z4;
    float rsum[2][4];
    #pragma unroll
    for (int a = 0; a < 2; ++a)
        #pragma unroll
        for (int j = 0; j < 4; ++j) rsum[a][j] = 0.f;
    __bf16* lPw = lP[wv];

    int cur = 0;
    for (int kt = 0; kt < 4; ++kt) {
        const bool pre = (kt < 3);
        bf16x8_t v8a, v8b;
        if (pre) {
            const __bf16* kb = base + 1024 + (size_t)(kt + 1) * 64 * 3072;
            #pragma unroll
            for (int q = 0; q < 2; ++q) {
                int c = (wv << 1) + q;
                int kl = (c << 3) + (lane >> 3);
                gload_lds16(kb + (size_t)kl * 3072 + (((lane & 7) ^ (lane >> 3)) << 3),
                            lKt[cur ^ 1] + c * 512);
            }
            const __bf16* vb = base + 2048 + (size_t)(kt + 1) * 64 * 3072;
            v8a = *(const bf16x8_t*)(vb + (size_t)(tid >> 3) * 3072 + ((tid & 7) << 3));
            v8b = *(const bf16x8_t*)(vb + (size_t)(32 + (tid >> 3)) * 3072 + ((tid & 7) << 3));
        }

        f32x4 s[2][4];
        #pragma unroll
        for (int a = 0; a < 2; ++a)
            #pragma unroll
            for (int b = 0; b < 4; ++b) s[a][b] = z4;
        #pragma unroll
        for (int ks = 0; ks < 2; ++ks) {
            bf16x8_t kf[4];
            #pragma unroll
            for (int ni = 0; ni < 4; ++ni)
                kf[ni] = lds_frag(lKt[cur], (ni << 4) + (lane & 15), (ks << 2) + (lane >> 4), 64);
            #pragma unroll
            for (int mi = 0; mi < 2; ++mi)
                #pragma unroll
                for (int ni = 0; ni < 4; ++ni)
                    s[mi][ni] = __builtin_amdgcn_mfma_f32_16x16x32_bf16(qf[mi][ks], kf[ni], s[mi][ni], 0, 0, 0);
        }

        #pragma unroll
        for (int mi = 0; mi < 2; ++mi) {
            #pragma unroll
            for (int j = 0; j < 4; ++j) {
                int qr = (wv << 5) + (mi << 4) + ((lane >> 4) << 2) + j;
                bf16x4_t th4 = *(const bf16x4_t*)(lTab + qr * 32 + (kt << 2));
                float rs = 0.f;
                #pragma unroll
                for (int ni = 0; ni < 4; ++ni) {
                    float p = __expf(s[mi][ni][j] * 0.125f + (float)th4[ni] + twv[mi][j]);
                    s[mi][ni][j] = p;
                    rs += p;
                }
                rsum[mi][j] += rs;
            }
        }

        #pragma unroll
        for (int hf = 0; hf < 2; ++hf) {
            #pragma unroll
            for (int mi = 0; mi < 2; ++mi) {
                #pragma unroll
                for (int j = 0; j < 4; ++j) {
                    int rl = (mi << 4) + ((lane >> 4) << 2) + j;
                    #pragma unroll
                    for (int b = 0; b < 2; ++b) {
                        int col = (b << 4) + (lane & 15);
                        lPw[rl * 32 + ((((col >> 3) ^ ((rl >> 1) & 3)) << 3) | (col & 7))] =
                            (__bf16)s[mi][(hf << 1) + b][j];
                    }
                }
            }
            bf16x8_t pf[2], vf[4];
            #pragma unroll
            for (int mi = 0; mi < 2; ++mi)
                pf[mi] = p_frag(lPw, (mi << 4) + (lane & 15), lane >> 4);
            #pragma unroll
            for (int no = 0; no < 4; ++no) {
                int d = (no << 4) + (lane & 15);
                vf[no] = *(const bf16x8_t*)(lVt[cur] + vt_addr(d, ((hf << 2) + (lane >> 4)) << 3));
            }
            #pragma unroll
            for (int mi = 0; mi < 2; ++mi)
                #pragma unroll
                for (int no = 0; no < 4; ++no)
                    oacc[mi][no] = __builtin_amdgcn_mfma_f32_16x16x32_bf16(pf[mi], vf[no], oacc[mi][no], 0, 0, 0);
        }

        if (pre) {
            int lc = tid & 7;
            #pragma unroll
            for (int e = 0; e < 8; ++e) {
                lVt[cur ^ 1][vt_addr(lc * 8 + e, tid >> 3)]        = v8a[e];
                lVt[cur ^ 1][vt_addr(lc * 8 + e, 32 + (tid >> 3))] = v8b[e];
            }
        }
        __syncthreads();
        cur ^= 1;
    }

    #pragma unroll
    for (int mi = 0; mi < 2; ++mi) {
        #pragma unroll
        for (int j = 0; j < 4; ++j) {
            float rs = rsum[mi][j];
            #pragma unroll
            for (int msk = 1; msk < 16; msk <<= 1) rs += __shfl_xor(rs, msk);
            float inv = 1.f / rs;
            int l = q0 + (wv << 5) + (mi << 4) + ((lane >> 4) << 2) + j;
            #pragma unroll
            for (int no = 0; no < 4; ++no) {
                int col = (no << 4) + (lane & 15);
                out[(size_t)(winc * 256 + l) * 1024 + h * 64 + col] = (__bf16)(oacc[mi][no][j] * inv);
            }
        }
    }
}

// ---------------------------------------------------------------------------
extern "C" void kernel_launch(void* const* d_in, const int* in_sizes, int n_in,
                              void* d_out, int out_size, void* d_ws, size_t ws_size,
                              hipStream_t stream) {
    const float* x      = (const float*)d_in[0];
    const float* c      = (const float*)d_in[1];
    const float* qkv_w  = (const float*)d_in[2];
    const float* qkv_b  = (const float*)d_in[3];
    const float* proj_w = (const float*)d_in[4];
    const float* proj_b = (const float*)d_in[5];
    const float* rel_h  = (const float*)d_in[6];
    const float* rel_w  = (const float*)d_in[7];
    const float* ada_w  = (const float*)d_in[8];
    const float* ada_b  = (const float*)d_in[9];
    const float* fc1_w  = (const float*)d_in[10];
    const float* fc1_b  = (const float*)d_in[11];
    const float* fc2_w  = (const float*)d_in[12];
    const float* fc2_b  = (const float*)d_in[13];
    float* xo = (float*)d_out;

    char* ws = (char*)d_ws;
    const size_t MB = 1ull << 20;
    int CH = 0;
    const int cands[7] = {16384, 8192, 4096, 2048, 1024, 512, 256};
    for (int i = 0; i < 7; ++i)
        if (26 * MB + (size_t)cands[i] * 10240 <= ws_size) { CH = cands[i]; break; }
    if (CH == 0) {
        zero_k<<<65536, 256, 0, stream>>>(xo, 16777216);
        return;
    }

    const int LDSB = 65536;
    hipFuncSetAttribute((const void*)&gemmw8<0>, hipFuncAttributeMaxDynamicSharedMemorySize, LDSB);
    hipFuncSetAttribute((const void*)&gemmw8<1>, hipFuncAttributeMaxDynamicSharedMemorySize, LDSB);
    hipFuncSetAttribute((const void*)&gemmw8<2>, hipFuncAttributeMaxDynamicSharedMemorySize, LDSB);
    hipFuncSetAttribute((const void*)&gemmw8<3>, hipFuncAttributeMaxDynamicSharedMemorySize, LDSB);

    const int NCH = 16384 / CH;
    float*  ws_silu = (float*)(ws);
    float*  ws_mod  = (float*)(ws + 65536);
    __bf16* w_qkv   = (__bf16*)(ws + 1 * MB);
    __bf16* w_proj  = (__bf16*)(ws + 7 * MB);
    __bf16* w_fc1   = (__bf16*)(ws + 9 * MB);
    __bf16* w_fc2   = (__bf16*)(ws + 17 * MB);
    __bf16* bufA    = (__bf16*)(ws + 26 * MB);
    __bf16* bufB    = (__bf16*)(ws + 26 * MB + (size_t)CH * 2048);

    silu_k   <<<16,   256, 0, stream>>>(c, ws_silu, 4096);
    mod_gemv <<<6144, 256, 0, stream>>>(ws_silu, ada_w, ada_b, ws_mod);
    conv_bf16<<<3072, 256, 0, stream>>>(qkv_w,  w_qkv,  786432);
    conv_bf16<<<1024, 256, 0, stream>>>(proj_w, w_proj, 262144);
    conv_bf16<<<4096, 256, 0, stream>>>(fc1_w,  w_fc1,  1048576);
    conv_bf16<<<4096, 256, 0, stream>>>(fc2_w,  w_fc2,  1048576);

    const int gy = CH / 128;
    for (int ci = 0; ci < NCH; ++ci) {
        int r0 = ci * CH;
        ln_mod_k<<<CH, 256, 0, stream>>>(x, ws_mod, 0, 1024, bufA, 1, r0);
        gemmw8<0><<<24 * gy, 512, LDSB, stream>>>(bufA, w_qkv, qkv_b, bufB,
                                                  nullptr, nullptr, 3072, 1024, r0, 24);
        attn_k<<<(CH / 256) * 32, 256, 0, stream>>>(bufB, rel_h, rel_w, bufA);
        gemmw8<1><<<8 * gy, 512, LDSB, stream>>>(bufA, w_proj, proj_b, xo,
                                                 x, ws_mod, 1024, 1024, r0, 8);
    }
    for (int ci = 0; ci < NCH; ++ci) {
        int r0 = ci * CH;
        ln_mod_k<<<CH, 256, 0, stream>>>(xo, ws_mod, 3072, 4096, bufA, 0, r0);
        gemmw8<2><<<32 * gy, 512, LDSB, stream>>>(bufA, w_fc1, fc1_b, bufB,
                                                  nullptr, nullptr, 4096, 1024, r0, 32);
        gemmw8<3><<<8 * gy, 512, LDSB, stream>>>(bufB, w_fc2, fc2_b, xo,
                                                 xo, ws_mod, 1024, 4096, r0, 8);
    }
}

// Round 16
// 624.448 us; speedup vs baseline: 1.0851x; 1.0851x over previous
//
#include <hip/hip_runtime.h>
#include <cstdint>
#include <cstddef>

// ---------------------------------------------------------------------------
// MultiStageDiT round 16: round-14 configuration restored (best: 630us).
// GEMM 256x256, 1 barrier + 1 vmcnt(0)/K-tile (7 schedule variants all
// plateau at ~35% MfmaUtil: LDS-read port and matrix pipe co-saturated at
// this geometry; occupancy proven non-binding in round 15).
// Only change vs round 14: four conv_bf16 launches fused into one.
// ---------------------------------------------------------------------------

typedef float  f32x4    __attribute__((ext_vector_type(4)));
typedef __bf16 bf16x8_t __attribute__((ext_vector_type(8)));
typedef __bf16 bf16x4_t __attribute__((ext_vector_type(4)));

#define DEV __device__ __forceinline__

DEV void gload_lds16(const void* g, void* l) {
    auto gp = (const uint32_t __attribute__((address_space(1)))*)(uintptr_t)g;
    auto lp = (uint32_t __attribute__((address_space(3)))*)(uint32_t)(uintptr_t)l;
    __builtin_amdgcn_global_load_lds(gp, lp, 16, 0, 0);
}

// row-major LDS tile, 16B chunks XOR-swizzled by (row&7)
DEV bf16x8_t lds_frag(const __bf16* base, int row, int chunk, int row_elems) {
    return *(const bf16x8_t*)(base + row * row_elems + ((chunk ^ (row & 7)) << 3));
}

// 32-elem-row P tile: XOR key (row>>1)&3
DEV bf16x8_t p_frag(const __bf16* base, int row, int chunk) {
    return *(const bf16x8_t*)(base + row * 32 + ((chunk ^ ((row >> 1) & 3)) << 3));
}

// V^T tile elem address: key (d&7)^((d>>3)&7)
DEV int vt_addr(int d, int k) {
    return d * 64 + ((((k >> 3) ^ (d & 7) ^ ((d >> 3) & 7)) << 3) | (k & 7));
}

DEV float gelu_tanh(float v) {
    float u = 0.7978845608028654f * (v + 0.044715f * v * v * v);
    float e = __expf(2.f * u);
    float th = 1.f - 2.f / (e + 1.f);
    return 0.5f * v * (1.f + th);
}

DEV int win2tok(int r) {
    int nb = r >> 12, wi = (r >> 8) & 15, l = r & 255;
    return (nb << 12) + (wi >> 2) * 1024 + (l >> 4) * 64 + (wi & 3) * 16 + (l & 15);
}

// ---------------------------------------------------------------------------
// prep kernels
// ---------------------------------------------------------------------------
__global__ void silu_k(const float* __restrict__ c, float* __restrict__ o, int n) {
    int i = blockIdx.x * 256 + threadIdx.x;
    if (i < n) { float v = c[i]; o[i] = v / (1.f + __expf(-v)); }
}

__global__ void zero_k(float* o, int n) {
    int i = blockIdx.x * 256 + threadIdx.x;
    if (i < n) o[i] = 0.f;
}

// all four weight matrices f32 -> bf16 in one dispatch (range-select source)
__global__ void conv_all_k(const float* __restrict__ s0, __bf16* __restrict__ d0,
                           const float* __restrict__ s1, __bf16* __restrict__ d1,
                           const float* __restrict__ s2, __bf16* __restrict__ d2,
                           const float* __restrict__ s3, __bf16* __restrict__ d3) {
    int i = blockIdx.x * 256 + threadIdx.x;          // float4 index, total 3145728
    const float4* s; bf16x4_t* d; int j;
    if (i < 786432)        { s = (const float4*)s0; d = (bf16x4_t*)d0; j = i; }
    else if (i < 1048576)  { s = (const float4*)s1; d = (bf16x4_t*)d1; j = i - 786432; }
    else if (i < 2097152)  { s = (const float4*)s2; d = (bf16x4_t*)d2; j = i - 1048576; }
    else                   { s = (const float4*)s3; d = (bf16x4_t*)d3; j = i - 2097152; }
    float4 v = s[j];
    bf16x4_t o; o[0] = (__bf16)v.x; o[1] = (__bf16)v.y; o[2] = (__bf16)v.z; o[3] = (__bf16)v.w;
    d[j] = o;
}

__global__ __launch_bounds__(256)
void mod_gemv(const float* __restrict__ sc, const float* __restrict__ w,
              const float* __restrict__ b, float* __restrict__ mod) {
    int o = (blockIdx.x << 2) + (threadIdx.x >> 6);
    int lane = threadIdx.x & 63;
    int n = o / 6144, col = o % 6144;
    const float4* wr = (const float4*)(w + (size_t)col * 1024);
    const float4* sr = (const float4*)(sc + n * 1024);
    float acc = 0.f;
    #pragma unroll 4
    for (int i = lane; i < 256; i += 64) {
        float4 a = wr[i], x = sr[i];
        acc += a.x * x.x + a.y * x.y + a.z * x.z + a.w * x.w;
    }
    #pragma unroll
    for (int m = 1; m < 64; m <<= 1) acc += __shfl_xor(acc, m);
    if (lane == 0) mod[o] = acc + b[col];
}

__global__ __launch_bounds__(256)
void ln_mod_k(const float* __restrict__ src, const float* __restrict__ mod,
              int sh_off, int sc_off, __bf16* __restrict__ out, int permute, int r0) {
    int rl = blockIdx.x;
    int r = rl + r0;
    int nb = r >> 12;
    int t = permute ? win2tok(r) : r;
    float4 v = ((const float4*)(src + (size_t)t * 1024))[threadIdx.x];
    float s  = v.x + v.y + v.z + v.w;
    float sq = v.x * v.x + v.y * v.y + v.z * v.z + v.w * v.w;
    #pragma unroll
    for (int m = 1; m < 64; m <<= 1) { s += __shfl_xor(s, m); sq += __shfl_xor(sq, m); }
    __shared__ float ps[4], pq[4];
    int wv = threadIdx.x >> 6, ln = threadIdx.x & 63;
    if (ln == 0) { ps[wv] = s; pq[wv] = sq; }
    __syncthreads();
    s  = ps[0] + ps[1] + ps[2] + ps[3];
    sq = pq[0] + pq[1] + pq[2] + pq[3];
    float mean = s * (1.f / 1024.f);
    float var  = sq * (1.f / 1024.f) - mean * mean;
    float rstd = rsqrtf(var + 1e-6f);
    int c = threadIdx.x << 2;
    const float* mrow = mod + nb * 6144;
    float4 scv = *(const float4*)(mrow + sc_off + c);
    float4 shv = *(const float4*)(mrow + sh_off + c);
    bf16x4_t o;
    o[0] = (__bf16)((v.x - mean) * rstd * (1.f + scv.x) + shv.x);
    o[1] = (__bf16)((v.y - mean) * rstd * (1.f + scv.y) + shv.y);
    o[2] = (__bf16)((v.z - mean) * rstd * (1.f + scv.z) + shv.z);
    o[3] = (__bf16)((v.w - mean) * rstd * (1.f + scv.w) + shv.w);
    *(bf16x4_t*)(out + (size_t)rl * 1024 + c) = o;
}

// ---------------------------------------------------------------------------
// 256x256 bf16 GEMM (round-11/14, best measured): 1 barrier + 1 vmcnt/K-tile.
// ---------------------------------------------------------------------------
template <int PM, int PN>
DEV void mfma16(f32x4 (&acc)[8][4], bf16x8_t (&fa)[4][2], bf16x8_t (&fb)[2][2][2]) {
    #pragma unroll
    for (int ks = 0; ks < 2; ++ks)
        #pragma unroll
        for (int mi = 0; mi < 4; ++mi)
            #pragma unroll
            for (int nn = 0; nn < 2; ++nn)
                acc[PM * 4 + mi][PN * 2 + nn] = __builtin_amdgcn_mfma_f32_16x16x32_bf16(
                    fa[mi][ks], fb[PN][nn][ks], acc[PM * 4 + mi][PN * 2 + nn], 0, 0, 0);
}

#define GBAR  __builtin_amdgcn_s_barrier()
#define PRIO1 __builtin_amdgcn_s_setprio(1)
#define PRIO0 __builtin_amdgcn_s_setprio(0)

template <int EPI>
__global__ __launch_bounds__(512)
void gemm256(const __bf16* __restrict__ A, const __bf16* __restrict__ B,
             const float* __restrict__ bias, void* __restrict__ Cout,
             const float* __restrict__ extra, const float* __restrict__ mod,
             int N, int K, int r0, int gx) {
    extern __shared__ __align__(16) char smem[];
    __bf16* lA = (__bf16*)smem;             // [2][256*64]
    __bf16* lB = lA + 2 * 16384;            // [2][256*64]
    const int tid = threadIdx.x, lane = tid & 63, wv = tid >> 6;
    const int wr = wv >> 2, wc = wv & 3;

    // bijective XCD-aware block swizzle (1-D grid)
    const int nwg = gridDim.x;
    const int qq = nwg >> 3, rr8 = nwg & 7;
    const int xcd = blockIdx.x & 7, pos = blockIdx.x >> 3;
    const int nid = (xcd < rr8 ? xcd * (qq + 1) : rr8 * (qq + 1) + (xcd - rr8) * qq) + pos;
    const int bm = (nid / gx) << 8, bn = (nid % gx) << 8;

    f32x4 acc[8][4];
    const f32x4 z4 = {0.f, 0.f, 0.f, 0.f};
    #pragma unroll
    for (int i = 0; i < 8; ++i)
        #pragma unroll
        for (int j = 0; j < 4; ++j) acc[i][j] = z4;

    bf16x8_t fa[4][2], fb[2][2][2];

    const int l8  = lane >> 3;
    const int gc8 = ((lane & 7) ^ l8) << 3;
    const int rbw = ((wv & 3) << 3) + ((wv >> 2) << 6);
    const __bf16* gA0 = A + (size_t)(bm +       (wv << 3) + l8) * K + gc8;
    const __bf16* gA1 = A + (size_t)(bm + 128 + (wv << 3) + l8) * K + gc8;
    const __bf16* gA2 = A + (size_t)(bm +  64 + (wv << 3) + l8) * K + gc8;
    const __bf16* gA3 = A + (size_t)(bm + 192 + (wv << 3) + l8) * K + gc8;
    const __bf16* gB0 = B + (size_t)(bn +       rbw + l8) * K + gc8;
    const __bf16* gB1 = B + (size_t)(bn + 128 + rbw + l8) * K + gc8;
    const __bf16* gB2 = B + (size_t)(bn +  32 + rbw + l8) * K + gc8;
    const __bf16* gB3 = B + (size_t)(bn + 160 + rbw + l8) * K + gc8;
    const int dA0 = (wv << 3) * 64, dA1 = (128 + (wv << 3)) * 64;
    const int dA2 = (64 + (wv << 3)) * 64, dA3 = (192 + (wv << 3)) * 64;
    const int dB0 = rbw * 64, dB1 = (128 + rbw) * 64;
    const int dB2 = (32 + rbw) * 64, dB3 = (160 + rbw) * 64;

    auto stageAll = [&](int be2) {
        gload_lds16(gA0, lA + be2 + dA0); gload_lds16(gA1, lA + be2 + dA1);
        gload_lds16(gB0, lB + be2 + dB0); gload_lds16(gB1, lB + be2 + dB1);
        gload_lds16(gB2, lB + be2 + dB2); gload_lds16(gB3, lB + be2 + dB3);
        gload_lds16(gA2, lA + be2 + dA2); gload_lds16(gA3, lA + be2 + dA3);
        gA0 += 64; gA1 += 64; gA2 += 64; gA3 += 64;
        gB0 += 64; gB1 += 64; gB2 += 64; gB3 += 64;
    };

    const int swzb = (lane >> 4) ^ (lane & 7);
    const __bf16* aR0 = lA + (wr << 13) + ((lane & 15) << 6) + (swzb << 3);
    const __bf16* aR1 = lA + (wr << 13) + ((lane & 15) << 6) + ((swzb ^ 4) << 3);
    const __bf16* bR0 = lB + (wc << 12) + ((lane & 15) << 6) + (swzb << 3);
    const __bf16* bR1 = lB + (wc << 12) + ((lane & 15) << 6) + ((swzb ^ 4) << 3);

    auto readA = [&](int be2, int pm) {
        #pragma unroll
        for (int mi = 0; mi < 4; ++mi) {
            fa[mi][0] = *(const bf16x8_t*)(aR0 + be2 + pm * 4096 + mi * 1024);
            fa[mi][1] = *(const bf16x8_t*)(aR1 + be2 + pm * 4096 + mi * 1024);
        }
    };
    auto readB = [&](int be2, int pn) {
        #pragma unroll
        for (int ni = 0; ni < 2; ++ni) {
            fb[pn][ni][0] = *(const bf16x8_t*)(bR0 + be2 + pn * 2048 + ni * 1024);
            fb[pn][ni][1] = *(const bf16x8_t*)(bR1 + be2 + pn * 2048 + ni * 1024);
        }
    };

    const int nt = K >> 6;
    stageAll(0);                         // prologue: tile 0 -> buf 0

    int be = 0;
    for (int t = 0; t < nt; ++t) {
        asm volatile("s_waitcnt vmcnt(0)" ::: "memory");
        GBAR;
        if (t + 1 < nt) stageAll(be ^ 16384);
        readA(be, 0); readB(be, 0); readB(be, 1);
        PRIO1; mfma16<0, 0>(acc, fa, fb); mfma16<0, 1>(acc, fa, fb); PRIO0;
        readA(be, 1);
        PRIO1; mfma16<1, 0>(acc, fa, fb); mfma16<1, 1>(acc, fa, fb); PRIO0;
        be ^= 16384;
    }

    // ---- epilogue ----
    #pragma unroll
    for (int am = 0; am < 8; ++am) {
        #pragma unroll
        for (int j = 0; j < 4; ++j) {
            int m = bm + (wr << 7) + (am << 4) + ((lane >> 4) << 2) + j;
            #pragma unroll
            for (int an = 0; an < 4; ++an) {
                int n = bn + (wc << 6) + (an << 4) + (lane & 15);
                float v = acc[am][an][j] + bias[n];
                if constexpr (EPI == 0) {
                    ((__bf16*)Cout)[(size_t)m * N + n] = (__bf16)v;
                } else if constexpr (EPI == 1) {
                    int mg = m + r0;
                    int tr = win2tok(mg);
                    float g = mod[(mg >> 12) * 6144 + 2048 + n];
                    ((float*)Cout)[(size_t)tr * 1024 + n] = extra[(size_t)tr * 1024 + n] + g * v;
                } else if constexpr (EPI == 2) {
                    ((__bf16*)Cout)[(size_t)m * N + n] = (__bf16)gelu_tanh(v);
                } else {
                    int mg = m + r0;
                    float g = mod[(mg >> 12) * 6144 + 5120 + n];
                    ((float*)Cout)[(size_t)mg * 1024 + n] = extra[(size_t)mg * 1024 + n] + g * v;
                }
            }
        }
    }
}

// ---------------------------------------------------------------------------
// Window attention + inline rel-pos tables (round-14, spill-free, passing).
// ---------------------------------------------------------------------------
__global__ __launch_bounds__(256, 3)
void attn_k(const __bf16* __restrict__ qkv, const float* __restrict__ relh,
            const float* __restrict__ relw, __bf16* __restrict__ out) {
    __shared__ __align__(16) __bf16 lP[4][32 * 32];
    __shared__ __align__(16) __bf16 lKt[2][64 * 64];
    __shared__ __align__(16) __bf16 lVt[2][64 * 64];
    __shared__ __align__(16) __bf16 lTab[128 * 32];

    const int blk = blockIdx.x;
    const int winc = blk >> 5, h = (blk >> 1) & 15, qh = blk & 1;
    const int tid = threadIdx.x, lane = tid & 63, wv = tid >> 6;
    const __bf16* base = qkv + (size_t)winc * 256 * 3072 + h * 64;
    const int q0 = qh << 7;

    {
        __bf16* lR0 = lKt[0];
        __bf16* lR1 = lKt[1];
        for (int i = tid; i < 1984; i += 256) {
            int row = i >> 6, c = i & 63;
            lR0[row * 72 + c] = (__bf16)relh[i];
            lR1[row * 72 + c] = (__bf16)relw[i];
        }
    }
    __syncthreads();
    {
        const int r = tid >> 1, half = tid & 1;
        const int lwin = q0 + r;
        const int qi = lwin >> 4, qj = lwin & 15;
        const __bf16* qrow = base + (size_t)lwin * 3072;
        float ah[8], aw[8];
        #pragma unroll
        for (int kk = 0; kk < 8; ++kk) { ah[kk] = 0.f; aw[kk] = 0.f; }
        for (int c8 = 0; c8 < 8; ++c8) {
            bf16x8_t q8 = *(const bf16x8_t*)(qrow + (c8 << 3));
            float qf8[8];
            #pragma unroll
            for (int e = 0; e < 8; ++e) qf8[e] = (float)q8[e];
            #pragma unroll
            for (int kk = 0; kk < 8; ++kk) {
                int kg = (half << 3) + kk;
                bf16x8_t r1 = *(const bf16x8_t*)(lKt[0] + (qi - kg + 15) * 72 + (c8 << 3));
                bf16x8_t r2 = *(const bf16x8_t*)(lKt[1] + (qj - kg + 15) * 72 + (c8 << 3));
                float a1 = 0.f, a2 = 0.f;
                #pragma unroll
                for (int e = 0; e < 8; ++e) {
                    a1 += qf8[e] * (float)r1[e];
                    a2 += qf8[e] * (float)r2[e];
                }
                ah[kk] += a1; aw[kk] += a2;
            }
        }
        bf16x8_t oh, ow;
        #pragma unroll
        for (int kk = 0; kk < 8; ++kk) { oh[kk] = (__bf16)ah[kk]; ow[kk] = (__bf16)aw[kk]; }
        *(bf16x8_t*)(lTab + r * 32 + (half << 3))      = oh;
        *(bf16x8_t*)(lTab + r * 32 + 16 + (half << 3)) = ow;
    }
    __syncthreads();

    bf16x8_t qf[2][2];
    #pragma unroll
    for (int mi = 0; mi < 2; ++mi)
        #pragma unroll
        for (int ks = 0; ks < 2; ++ks) {
            int l = q0 + (wv << 5) + (mi << 4) + (lane & 15);
            qf[mi][ks] = *(const bf16x8_t*)(base + (size_t)l * 3072 + (((ks << 2) + (lane >> 4)) << 3));
        }
    {
        const __bf16* kb = base + 1024;
        #pragma unroll
        for (int q = 0; q < 2; ++q) {
            int c = (wv << 1) + q;
            int kl = (c << 3) + (lane >> 3);
            gload_lds16(kb + (size_t)kl * 3072 + (((lane & 7) ^ (lane >> 3)) << 3),
                        lKt[0] + c * 512);
        }
        const __bf16* vb = base + 2048;
        bf16x8_t a = *(const bf16x8_t*)(vb + (size_t)(tid >> 3) * 3072 + ((tid & 7) << 3));
        bf16x8_t b = *(const bf16x8_t*)(vb + (size_t)(32 + (tid >> 3)) * 3072 + ((tid & 7) << 3));
        int lc = tid & 7;
        #pragma unroll
        for (int e = 0; e < 8; ++e) {
            lVt[0][vt_addr(lc * 8 + e, tid >> 3)]        = a[e];
            lVt[0][vt_addr(lc * 8 + e, 32 + (tid >> 3))] = b[e];
        }
    }
    __syncthreads();

    float twv[2][4];
    #pragma unroll
    for (int mi = 0; mi < 2; ++mi)
        #pragma unroll
        for (int j = 0; j < 4; ++j) {
            int qr = (wv << 5) + (mi << 4) + ((lane >> 4) << 2) + j;
            twv[mi][j] = (float)lTab[qr * 32 + 16 + (lane & 15)];
        }

    const f32x4 z4 = {0.f, 0.f, 0.f, 0.f};
    f32x4 oacc[2][4];
    #pragma unroll
    for (int a = 0; a < 2; ++a)
        #pragma unroll
        for (int b = 0; b < 4; ++b) oacc[a][b] = z4;
    float rsum[2][4];
    #pragma unroll
    for (int a = 0; a < 2; ++a)
        #pragma unroll
        for (int j = 0; j < 4; ++j) rsum[a][j] = 0.f;
    __bf16* lPw = lP[wv];

    int cur = 0;
    for (int kt = 0; kt < 4; ++kt) {
        const bool pre = (kt < 3);
        bf16x8_t v8a, v8b;
        if (pre) {
            const __bf16* kb = base + 1024 + (size_t)(kt + 1) * 64 * 3072;
            #pragma unroll
            for (int q = 0; q < 2; ++q) {
                int c = (wv << 1) + q;
                int kl = (c << 3) + (lane >> 3);
                gload_lds16(kb + (size_t)kl * 3072 + (((lane & 7) ^ (lane >> 3)) << 3),
                            lKt[cur ^ 1] + c * 512);
            }
            const __bf16* vb = base + 2048 + (size_t)(kt + 1) * 64 * 3072;
            v8a = *(const bf16x8_t*)(vb + (size_t)(tid >> 3) * 3072 + ((tid & 7) << 3));
            v8b = *(const bf16x8_t*)(vb + (size_t)(32 + (tid >> 3)) * 3072 + ((tid & 7) << 3));
        }

        f32x4 s[2][4];
        #pragma unroll
        for (int a = 0; a < 2; ++a)
            #pragma unroll
            for (int b = 0; b < 4; ++b) s[a][b] = z4;
        #pragma unroll
        for (int ks = 0; ks < 2; ++ks) {
            bf16x8_t kf[4];
            #pragma unroll
            for (int ni = 0; ni < 4; ++ni)
                kf[ni] = lds_frag(lKt[cur], (ni << 4) + (lane & 15), (ks << 2) + (lane >> 4), 64);
            #pragma unroll
            for (int mi = 0; mi < 2; ++mi)
                #pragma unroll
                for (int ni = 0; ni < 4; ++ni)
                    s[mi][ni] = __builtin_amdgcn_mfma_f32_16x16x32_bf16(qf[mi][ks], kf[ni], s[mi][ni], 0, 0, 0);
        }

        #pragma unroll
        for (int mi = 0; mi < 2; ++mi) {
            #pragma unroll
            for (int j = 0; j < 4; ++j) {
                int qr = (wv << 5) + (mi << 4) + ((lane >> 4) << 2) + j;
                bf16x4_t th4 = *(const bf16x4_t*)(lTab + qr * 32 + (kt << 2));
                float rs = 0.f;
                #pragma unroll
                for (int ni = 0; ni < 4; ++ni) {
                    float p = __expf(s[mi][ni][j] * 0.125f + (float)th4[ni] + twv[mi][j]);
                    s[mi][ni][j] = p;
                    rs += p;
                }
                rsum[mi][j] += rs;
            }
        }

        #pragma unroll
        for (int hf = 0; hf < 2; ++hf) {
            #pragma unroll
            for (int mi = 0; mi < 2; ++mi) {
                #pragma unroll
                for (int j = 0; j < 4; ++j) {
                    int rl = (mi << 4) + ((lane >> 4) << 2) + j;
                    #pragma unroll
                    for (int b = 0; b < 2; ++b) {
                        int col = (b << 4) + (lane & 15);
                        lPw[rl * 32 + ((((col >> 3) ^ ((rl >> 1) & 3)) << 3) | (col & 7))] =
                            (__bf16)s[mi][(hf << 1) + b][j];
                    }
                }
            }
            bf16x8_t pf[2], vf[4];
            #pragma unroll
            for (int mi = 0; mi < 2; ++mi)
                pf[mi] = p_frag(lPw, (mi << 4) + (lane & 15), lane >> 4);
            #pragma unroll
            for (int no = 0; no < 4; ++no) {
                int d = (no << 4) + (lane & 15);
                vf[no] = *(const bf16x8_t*)(lVt[cur] + vt_addr(d, ((hf << 2) + (lane >> 4)) << 3));
            }
            #pragma unroll
            for (int mi = 0; mi < 2; ++mi)
                #pragma unroll
                for (int no = 0; no < 4; ++no)
                    oacc[mi][no] = __builtin_amdgcn_mfma_f32_16x16x32_bf16(pf[mi], vf[no], oacc[mi][no], 0, 0, 0);
        }

        if (pre) {
            int lc = tid & 7;
            #pragma unroll
            for (int e = 0; e < 8; ++e) {
                lVt[cur ^ 1][vt_addr(lc * 8 + e, tid >> 3)]        = v8a[e];
                lVt[cur ^ 1][vt_addr(lc * 8 + e, 32 + (tid >> 3))] = v8b[e];
            }
        }
        __syncthreads();
        cur ^= 1;
    }

    #pragma unroll
    for (int mi = 0; mi < 2; ++mi) {
        #pragma unroll
        for (int j = 0; j < 4; ++j) {
            float rs = rsum[mi][j];
            #pragma unroll
            for (int msk = 1; msk < 16; msk <<= 1) rs += __shfl_xor(rs, msk);
            float inv = 1.f / rs;
            int l = q0 + (wv << 5) + (mi << 4) + ((lane >> 4) << 2) + j;
            #pragma unroll
            for (int no = 0; no < 4; ++no) {
                int col = (no << 4) + (lane & 15);
                out[(size_t)(winc * 256 + l) * 1024 + h * 64 + col] = (__bf16)(oacc[mi][no][j] * inv);
            }
        }
    }
}

// ---------------------------------------------------------------------------
extern "C" void kernel_launch(void* const* d_in, const int* in_sizes, int n_in,
                              void* d_out, int out_size, void* d_ws, size_t ws_size,
                              hipStream_t stream) {
    const float* x      = (const float*)d_in[0];
    const float* c      = (const float*)d_in[1];
    const float* qkv_w  = (const float*)d_in[2];
    const float* qkv_b  = (const float*)d_in[3];
    const float* proj_w = (const float*)d_in[4];
    const float* proj_b = (const float*)d_in[5];
    const float* rel_h  = (const float*)d_in[6];
    const float* rel_w  = (const float*)d_in[7];
    const float* ada_w  = (const float*)d_in[8];
    const float* ada_b  = (const float*)d_in[9];
    const float* fc1_w  = (const float*)d_in[10];
    const float* fc1_b  = (const float*)d_in[11];
    const float* fc2_w  = (const float*)d_in[12];
    const float* fc2_b  = (const float*)d_in[13];
    float* xo = (float*)d_out;

    char* ws = (char*)d_ws;
    const size_t MB = 1ull << 20;
    int CH = 0;
    const int cands[7] = {16384, 8192, 4096, 2048, 1024, 512, 256};
    for (int i = 0; i < 7; ++i)
        if (26 * MB + (size_t)cands[i] * 10240 <= ws_size) { CH = cands[i]; break; }
    if (CH == 0) {
        zero_k<<<65536, 256, 0, stream>>>(xo, 16777216);
        return;
    }

    const int LDSB = 131072;
    hipFuncSetAttribute((const void*)&gemm256<0>, hipFuncAttributeMaxDynamicSharedMemorySize, LDSB);
    hipFuncSetAttribute((const void*)&gemm256<1>, hipFuncAttributeMaxDynamicSharedMemorySize, LDSB);
    hipFuncSetAttribute((const void*)&gemm256<2>, hipFuncAttributeMaxDynamicSharedMemorySize, LDSB);
    hipFuncSetAttribute((const void*)&gemm256<3>, hipFuncAttributeMaxDynamicSharedMemorySize, LDSB);

    const int NCH = 16384 / CH;
    float*  ws_silu = (float*)(ws);
    float*  ws_mod  = (float*)(ws + 65536);
    __bf16* w_qkv   = (__bf16*)(ws + 1 * MB);
    __bf16* w_proj  = (__bf16*)(ws + 7 * MB);
    __bf16* w_fc1   = (__bf16*)(ws + 9 * MB);
    __bf16* w_fc2   = (__bf16*)(ws + 17 * MB);
    __bf16* bufA    = (__bf16*)(ws + 26 * MB);
    __bf16* bufB    = (__bf16*)(ws + 26 * MB + (size_t)CH * 2048);

    silu_k    <<<16,    256, 0, stream>>>(c, ws_silu, 4096);
    mod_gemv  <<<6144,  256, 0, stream>>>(ws_silu, ada_w, ada_b, ws_mod);
    conv_all_k<<<12288, 256, 0, stream>>>(qkv_w, w_qkv, proj_w, w_proj,
                                          fc1_w, w_fc1, fc2_w, w_fc2);

    const int gy = CH / 256;
    for (int ci = 0; ci < NCH; ++ci) {
        int r0 = ci * CH;
        ln_mod_k<<<CH, 256, 0, stream>>>(x, ws_mod, 0, 1024, bufA, 1, r0);
        gemm256<0><<<12 * gy, 512, LDSB, stream>>>(bufA, w_qkv, qkv_b, bufB,
                                                   nullptr, nullptr, 3072, 1024, r0, 12);
        attn_k<<<(CH / 256) * 32, 256, 0, stream>>>(bufB, rel_h, rel_w, bufA);
        gemm256<1><<<4 * gy, 512, LDSB, stream>>>(bufA, w_proj, proj_b, xo,
                                                  x, ws_mod, 1024, 1024, r0, 4);
    }
    for (int ci = 0; ci < NCH; ++ci) {
        int r0 = ci * CH;
        ln_mod_k<<<CH, 256, 0, stream>>>(xo, ws_mod, 3072, 4096, bufA, 0, r0);
        gemm256<2><<<16 * gy, 512, LDSB, stream>>>(bufA, w_fc1, fc1_b, bufB,
                                                   nullptr, nullptr, 4096, 1024, r0, 16);
        gemm256<3><<<4 * gy, 512, LDSB, stream>>>(bufB, w_fc2, fc2_b, xo,
                                                  xo, ws_mod, 1024, 4096, r0, 4);
    }
}